// Round 8
// baseline (126.353 us; speedup 1.0000x reference)
//
#include <hip/hip_runtime.h>

// ContextGuidedTokenShift on MI355X.
// x: (B=8, N=16384, C=576) f32, H=W=128. out = w*shift(x) + (1-w)*x
// Channel slabs (widths all multiples of 16 floats) each have a fixed (dy,dx).
// shifted[y,x] = in[y-dy, x-dx] if in bounds else 0.
//
// R8: R5 (1 float4/thread, NT streaming store — R7 proved NT worth ~2.5%)
// + persistent grid-stride: 2048 blocks (256 CU x 8) x 36 iterations,
// amortizing per-block dispatch/kernarg/prologue overhead 36x (G11).
// Each block owns a contiguous 144KB run; XCD swizzle keeps each XCD on a
// contiguous 37.75MB region so the +/-2-row shift window hits its L2.

#define B_   8
#define HW_  128
#define N_   16384      // HW_*HW_
#define C_   576
#define C4_  144        // C_/4
#define NXCD 8

typedef float f32x4 __attribute__((ext_vector_type(4)));

// nibble s = (d + 2); dy/dx per slab s in [0,16)
#define DY_PACK 0x0404131304221322ULL
#define DX_PACK 0x4004311322042213ULL

__global__ __launch_bounds__(256) void cgts_kernel(const float* __restrict__ in,
                                                   const float* __restrict__ wptr,
                                                   float* __restrict__ out,
                                                   int iters) {
    // XCD-aware swizzle: grid = 2048 blocks, divisible by 8 -> bijective.
    const int bid = blockIdx.x;
    const int swz = (bid & (NXCD - 1)) * (int)(gridDim.x >> 3) + (bid >> 3);

    const float w   = wptr[0];
    const float omw = 1.0f - w;

    int idx = swz * (iters << 8) + (int)threadIdx.x;   // float4 index

    #pragma unroll 1
    for (int i = 0; i < iters; ++i, idx += 256) {
        // decompose flat float4 index -> (b, token, channel4)
        const int c4 = idx % C4_;          // magic-mul division
        const int t  = idx / C4_;          // b*N + n
        const int n  = t & (N_ - 1);
        const int b  = t >> 14;            // N_ = 2^14
        const int y  = n >> 7;             // HW_ = 2^7
        const int xc = n & (HW_ - 1);
        const int c  = c4 << 2;

        // slab index -> offset (pure VALU via packed nibbles)
        int s;
        if (c < 256)      s = c >> 6;
        else if (c < 512) s = 4 + ((c - 256) >> 5);
        else              s = 12 + ((c - 512) >> 4);
        const int sh4 = s << 2;
        const int dy = (int)((DY_PACK >> sh4) & 0xF) - 2;
        const int dx = (int)((DX_PACK >> sh4) & 0xF) - 2;

        // self load: flat float index = 4*idx (lane-contiguous 16B)
        const f32x4 self = *reinterpret_cast<const f32x4*>(in + (size_t)idx * 4);

        const int sy = y - dy;
        const int sx = xc - dx;
        f32x4 sh = (f32x4){0.f, 0.f, 0.f, 0.f};
        if ((unsigned)sy < (unsigned)HW_ && (unsigned)sx < (unsigned)HW_) {
            const size_t sidx = ((size_t)(b * N_ + (sy << 7) + sx)) * C_ + c;
            sh = *reinterpret_cast<const f32x4*>(in + sidx);
        }

        f32x4 o;
        o.x = w * sh.x + omw * self.x;
        o.y = w * sh.y + omw * self.y;
        o.z = w * sh.z + omw * self.z;
        o.w = w * sh.w + omw * self.w;
        // streaming store: output is never re-read; keep L2/L3 for the input
        __builtin_nontemporal_store(o, reinterpret_cast<f32x4*>(out + (size_t)idx * 4));
    }
}

extern "C" void kernel_launch(void* const* d_in, const int* in_sizes, int n_in,
                              void* d_out, int out_size, void* d_ws, size_t ws_size,
                              hipStream_t stream) {
    const float* x = (const float*)d_in[0];
    const float* w = (const float*)d_in[1];
    float* out = (float*)d_out;

    const int total4 = B_ * N_ * C4_;      // 18,874,368 float4 chunks
    const int blocks = 2048;               // 256 CU x 8 blocks, %8 == 0
    const int iters  = total4 / (blocks * 256);   // = 36 exactly
    cgts_kernel<<<blocks, 256, 0, stream>>>(x, w, out, iters);
}

// Round 9
// 110.433 us; speedup vs baseline: 1.1442x; 1.1442x over previous
//
#include <hip/hip_runtime.h>

// ContextGuidedTokenShift on MI355X — FINAL (revert to R5, best measured).
// x: (B=8, N=16384, C=576) f32, H=W=128. out = w*shift(x) + (1-w)*x
// Channel slabs (widths all multiples of 16 floats) each have a fixed (dy,dx).
// shifted[y,x] = in[y-dy, x-dx] if in bounds else 0.
//
// Proven structure (ledger R1-R8):
//   - 1 float4 per thread, lane i <-> base + 16B*i exact contiguity
//     (2-chunk/thread -7%, 32B/lane -15%, persistent loop -17%)
//   - XCD-aware bijective block swizzle: each XCD owns a contiguous 37.75MB
//     region so the +/-2-row shift window hits its private 4MB L2 (+7% w/ NT)
//   - nontemporal streaming stores: write-once output bypasses L2, preserving
//     input residency (+2.5% vs plain store)
//   - dy/dx as packed nibbles -> shifted-address chain is pure VALU
// 108.4-109.2 us = 5.57 TB/s effective on the 604MB logical stream = 88.5%
// of the measured float4-copy ceiling; HBM itself unsaturated (~460MB real
// traffic, input half-L3-resident) -> read-service-path bound.

#define B_   8
#define HW_  128
#define N_   16384      // HW_*HW_
#define C_   576
#define C4_  144        // C_/4
#define NXCD 8

typedef float f32x4 __attribute__((ext_vector_type(4)));

// nibble s = (d + 2); dy/dx per slab s in [0,16)
#define DY_PACK 0x0404131304221322ULL
#define DX_PACK 0x4004311322042213ULL

__global__ __launch_bounds__(256) void cgts_kernel(const float* __restrict__ in,
                                                   const float* __restrict__ wptr,
                                                   float* __restrict__ out) {
    // XCD-aware swizzle: grid = 73728 blocks, divisible by 8 -> bijective.
    const int bid = blockIdx.x;
    const int swz = (bid & (NXCD - 1)) * (int)(gridDim.x / NXCD) + (bid >> 3);
    const int idx = swz * 256 + (int)threadIdx.x;   // float4 index

    const float w   = wptr[0];
    const float omw = 1.0f - w;

    // decompose flat float4 index -> (b, token, channel4)
    const int c4 = idx % C4_;          // magic-mul division
    const int t  = idx / C4_;          // b*N + n
    const int n  = t & (N_ - 1);
    const int b  = t >> 14;            // N_ = 2^14
    const int y  = n >> 7;             // HW_ = 2^7
    const int xc = n & (HW_ - 1);
    const int c  = c4 << 2;

    // slab index -> offset (pure VALU via packed nibbles)
    int s;
    if (c < 256)      s = c >> 6;
    else if (c < 512) s = 4 + ((c - 256) >> 5);
    else              s = 12 + ((c - 512) >> 4);
    const int sh4 = s << 2;
    const int dy = (int)((DY_PACK >> sh4) & 0xF) - 2;
    const int dx = (int)((DX_PACK >> sh4) & 0xF) - 2;

    // self load: flat float index = 4*idx (contiguous within each XCD chunk)
    const f32x4 self = *reinterpret_cast<const f32x4*>(in + (size_t)idx * 4);

    const int sy = y - dy;
    const int sx = xc - dx;
    f32x4 sh = (f32x4){0.f, 0.f, 0.f, 0.f};
    if ((unsigned)sy < (unsigned)HW_ && (unsigned)sx < (unsigned)HW_) {
        const size_t sidx = ((size_t)(b * N_ + (sy << 7) + sx)) * C_ + c;
        sh = *reinterpret_cast<const f32x4*>(in + sidx);
    }

    f32x4 o;
    o.x = w * sh.x + omw * self.x;
    o.y = w * sh.y + omw * self.y;
    o.z = w * sh.z + omw * self.z;
    o.w = w * sh.w + omw * self.w;
    // streaming store: output is never re-read; keep L2/L3 for the input
    __builtin_nontemporal_store(o, reinterpret_cast<f32x4*>(out + (size_t)idx * 4));
}

extern "C" void kernel_launch(void* const* d_in, const int* in_sizes, int n_in,
                              void* d_out, int out_size, void* d_ws, size_t ws_size,
                              hipStream_t stream) {
    const float* x = (const float*)d_in[0];
    const float* w = (const float*)d_in[1];
    float* out = (float*)d_out;

    const int total4 = B_ * N_ * C4_;          // 18,874,368 float4 chunks
    const int blocks = total4 / 256;           // 73,728 (exact, divisible by 8)
    cgts_kernel<<<blocks, 256, 0, stream>>>(x, w, out);
}